// Round 2
// baseline (334.257 us; speedup 1.0000x reference)
//
#include <hip/hip_runtime.h>

// DepConv3D, fused single-pass, 4-row x 256-px tile, 512 threads (8 waves).
//   diff = depth[nbr]-depth[center]; kd=0 iff diff==-1, kd=1 iff diff==0, else 0.
// Block stages a 6x258 halo tile (bf16 pixel-major features, 40 B padded px
// stride + int depth) in LDS once, then each wave runs the 9-tap MFMA loop for
// one half-row (8 its x 16 px) reading LDS only (base VGPR + imm offsets).
// LDS write pattern: per thread 2x ds_write_b64 (8 ics of one px) at 40 B px
// stride -> uniform bank floor (gcd(10,32)=2). Reads: b64 at 40 B stride, also
// floor. MFMA 16x16x32_bf16 conventions (validated by previous passing runs):
//   A: m=lane&15 (oc), kk=(lane>>4)*8+j ; B: n=lane&15 (pixel), kk same
//   D: col=lane&15 (pixel), row=(lane>>4)*4+r (oc)

#define IC 16
#define OC 32
#define Hh 512
#define Ww 512
#define HW (Hh * Ww)
#define TW 256          // tile width  (output px)
#define TR 4            // tile rows   (output)
#define PXS 20          // shorts per px in LDS (40 B, padded from 32)

typedef __attribute__((ext_vector_type(8))) short short8;
typedef __attribute__((ext_vector_type(4))) float float4v;
typedef __attribute__((ext_vector_type(2))) unsigned int uint2v;

__device__ __forceinline__ unsigned short f2bf(float x) {
    unsigned u = __float_as_uint(x);
    unsigned r = u + 0x7FFFu + ((u >> 16) & 1u);   // RNE
    return (unsigned short)(r >> 16);
}

// ---- prepass: fp32 weights (32,16,3,3,3) -> bf16 A-fragments ----
__global__ void prep_weights(const float* __restrict__ wgt,
                             unsigned short* __restrict__ wsA) {
    int e = blockIdx.x * 256 + threadIdx.x;
    if (e >= 9 * 2 * 64 * 8) return;
    int j    = e & 7;
    int lane = (e >> 3) & 63;
    int mt   = (e >> 9) & 1;
    int c    = e >> 10;
    int oc = mt * 16 + (lane & 15);
    int kk = ((lane >> 4) << 3) + j;
    wsA[e] = f2bf(wgt[oc * 432 + (kk >> 1) * 27 + (kk & 1) * 9 + c]);
}

// ---- fused main kernel ----
__global__ __launch_bounds__(512, 4) void depconv_fused(
    const float* __restrict__ feat,           // (4,16,512,512) fp32
    const int*   __restrict__ depth,          // (4,512,512)
    const unsigned short* __restrict__ wsA,
    float*       __restrict__ out)            // (4,32,512,512)
{
    __shared__ unsigned short ftile[TR + 2][TW + 2][PXS];   // 61,920 B
    __shared__ int            dtile[TR + 2][TW + 2];        //  6,192 B

    const int tid = threadIdx.x;

    // XCD bijective swizzle: 1024 blocks, 8 XCDs, 1024%8==0.
    const int bid = blockIdx.x;
    const int wg  = (bid & 7) * (1024 / 8) + (bid >> 3);

    const int b      = wg >> 8;            // image (256 blocks per image)
    const int rowblk = (wg >> 1) & 127;
    const int colblk = wg & 1;
    const int h0     = rowblk * TR;
    const int wstart = colblk * TW;

    // ---- stage 6x258 halo tile ----
    {
        const int h8 = tid >> 8;           // ic-half: ics 8*h8 .. 8*h8+7 (wave-uniform)
        const int xl = tid & 255;          // tile x (main body)
        const int x  = wstart - 1 + xl;
        const int xc = x < 0 ? 0 : (x > Ww - 1 ? Ww - 1 : x);
        const int xt  = wstart - 1 + 256 + xl;          // tail px 256,257 (xl<2)
        const int xct = xt > Ww - 1 ? Ww - 1 : xt;
        const float* fb  = feat + (size_t)(b * IC + 8 * h8) * HW;
        const int*   dbp = depth + (b << 18);
#pragma unroll
        for (int r = 0; r < 6; ++r) {
            int y = h0 - 1 + r;
            y = y < 0 ? 0 : (y > Hh - 1 ? Hh - 1 : y);
            const float* fpl = fb + (size_t)y * Ww;
            if (h8 == 0) {
                dtile[r][xl] = dbp[y * Ww + xc];
                if (xl < 2) dtile[r][256 + xl] = dbp[y * Ww + xct];
            }
            unsigned pk[4];
#pragma unroll
            for (int i = 0; i < 4; ++i) {
                float a = fpl[(size_t)(2 * i) * HW + xc];
                float c = fpl[(size_t)(2 * i + 1) * HW + xc];
                pk[i] = (unsigned)f2bf(a) | ((unsigned)f2bf(c) << 16);
            }
            unsigned short* wp = &ftile[r][xl][h8 * 8];
            *(uint2v*)wp       = (uint2v){pk[0], pk[1]};
            *(uint2v*)(wp + 4) = (uint2v){pk[2], pk[3]};
            if (xl < 2) {
                unsigned qk[4];
#pragma unroll
                for (int i = 0; i < 4; ++i) {
                    float a = fpl[(size_t)(2 * i) * HW + xct];
                    float c = fpl[(size_t)(2 * i + 1) * HW + xct];
                    qk[i] = (unsigned)f2bf(a) | ((unsigned)f2bf(c) << 16);
                }
                unsigned short* wq = &ftile[r][256 + xl][h8 * 8];
                *(uint2v*)wq       = (uint2v){qk[0], qk[1]};
                *(uint2v*)(wq + 4) = (uint2v){qk[2], qk[3]};
            }
        }
    }

    // A-fragments (global, all waves same -> L2 broadcast; no LDS dependency)
    const int lane = tid & 63;
    short8 afrag[9][2];
    {
        const short8* ap = (const short8*)wsA;
#pragma unroll
        for (int c = 0; c < 9; ++c) {
            afrag[c][0] = ap[(c * 2 + 0) * 64 + lane];
            afrag[c][1] = ap[(c * 2 + 1) * 64 + lane];
        }
    }
    __syncthreads();

    const int wv   = tid >> 6;
    const int g    = lane >> 4;     // ic-group: ics 4g..4g+3
    const int n    = lane & 15;
    const int rr   = wv >> 1;       // output row within tile: 0..3
    const int h    = h0 + rr;
    const int xoff = (wv & 1) * 128;

    const bool topE = (h == 0);
    const bool botE = (h == Hh - 1);

    float* opb = out + ((size_t)(b * OC) << 18) + (size_t)h * Ww;

    for (int it = 0; it < 8; ++it) {
        const int xb = xoff + it * 16 + n;      // tile px [0,256)
        const int w  = wstart + xb;             // global column
        const int dc = dtile[rr + 1][xb + 1];
        const bool lftE = (w == 0);
        const bool rgtE = (w == Ww - 1);

        float4v acc0 = {0.f, 0.f, 0.f, 0.f};
        float4v acc1 = {0.f, 0.f, 0.f, 0.f};

#pragma unroll
        for (int t = 0; t < 9; ++t) {
            const int kh = t / 3, kw = t % 3;
            unsigned mm;
            if (t == 4) {
                mm = 0xffff0000u;   // center: diff==0 always, kd=1 slice
            } else {
                const bool inb = !((kh == 0 && topE) || (kh == 2 && botE) ||
                                   (kw == 0 && lftE) || (kw == 2 && rgtE));
                const int diff = dtile[rr + kh][xb + kw] - dc;
                mm = (diff == 0) ? 0xffff0000u : ((diff == -1) ? 0x0000ffffu : 0u);
                if (!inb) mm = 0u;
            }
            // 4 ics of this lane's neighbor pixel: one 8 B LDS read,
            // single base VGPR + immediate offset ((kh*258+kw)*40 < 64 KiB).
            const uint2v pr = *(const uint2v*)(&ftile[rr + kh][xb + kw][g << 2]);
            union { short8 s; unsigned u[4]; } bf;
            bf.u[0] = __builtin_amdgcn_perm(0u, pr.x, 0x01000100u) & mm;  // ic 4g+0
            bf.u[1] = __builtin_amdgcn_perm(0u, pr.x, 0x03020302u) & mm;  // ic 4g+1
            bf.u[2] = __builtin_amdgcn_perm(0u, pr.y, 0x01000100u) & mm;  // ic 4g+2
            bf.u[3] = __builtin_amdgcn_perm(0u, pr.y, 0x03020302u) & mm;  // ic 4g+3

            acc0 = __builtin_amdgcn_mfma_f32_16x16x32_bf16(afrag[t][0], bf.s, acc0, 0, 0, 0);
            acc1 = __builtin_amdgcn_mfma_f32_16x16x32_bf16(afrag[t][1], bf.s, acc1, 0, 0, 0);
        }

        const int rbase = g * 4;
        float* op = opb + w;
#pragma unroll
        for (int r = 0; r < 4; ++r) {
            op[(size_t)(rbase + r) * HW]      = acc0[r];
            op[(size_t)(16 + rbase + r) * HW] = acc1[r];
        }
    }
}

extern "C" void kernel_launch(void* const* d_in, const int* in_sizes, int n_in,
                              void* d_out, int out_size, void* d_ws, size_t ws_size,
                              hipStream_t stream) {
    const float* feat  = (const float*)d_in[0];
    const int*   depth = (const int*)d_in[1];
    const float* wgt   = (const float*)d_in[2];
    float* out = (float*)d_out;

    unsigned short* wsA = (unsigned short*)d_ws;     // 18,432 B only

    prep_weights<<<36, 256, 0, stream>>>(wgt, wsA);
    depconv_fused<<<1024, 512, 0, stream>>>(feat, depth, wsA, out);
}

// Round 3
// 223.719 us; speedup vs baseline: 1.4941x; 1.4941x over previous
//
#include <hip/hip_runtime.h>

// DepConv3D, fused single-pass, 4-row x 256-px tile, 512 threads (8 waves).
//   diff = depth[nbr]-depth[center]; kd=0 iff diff==-1, kd=1 iff diff==0, else 0.
// Block stages a 6x258 halo tile (bf16 pixel-major features, 40 B padded px
// stride + int depth) in LDS once, then each wave runs the 9-tap MFMA loop for
// one half-row (8 its x 16 px) reading LDS only (base VGPR + imm offsets).
// LDS write pattern: per thread 2x ds_write_b64 (8 ics of one px) at 40 B px
// stride -> uniform bank floor (gcd(10,32)=2). Reads: b64 at 40 B stride, also
// floor. MFMA 16x16x32_bf16 conventions (validated by previous passing runs):
//   A: m=lane&15 (oc), kk=(lane>>4)*8+j ; B: n=lane&15 (pixel), kk same
//   D: col=lane&15 (pixel), row=(lane>>4)*4+r (oc)
// __launch_bounds__(512, 2): R2's (512,4) capped the allocator at 64 VGPRs
// (afrag alone needs 72) -> catastrophic scratch spill (WRITE_SIZE 320 MB).
// (512,2) caps at 128 VGPRs = 16 waves/CU, matching the LDS-bound occupancy.

#define IC 16
#define OC 32
#define Hh 512
#define Ww 512
#define HW (Hh * Ww)
#define TW 256          // tile width  (output px)
#define TR 4            // tile rows   (output)
#define PXS 20          // shorts per px in LDS (40 B, padded from 32)

typedef __attribute__((ext_vector_type(8))) short short8;
typedef __attribute__((ext_vector_type(4))) float float4v;
typedef __attribute__((ext_vector_type(2))) unsigned int uint2v;

__device__ __forceinline__ unsigned short f2bf(float x) {
    unsigned u = __float_as_uint(x);
    unsigned r = u + 0x7FFFu + ((u >> 16) & 1u);   // RNE
    return (unsigned short)(r >> 16);
}

// ---- prepass: fp32 weights (32,16,3,3,3) -> bf16 A-fragments ----
__global__ void prep_weights(const float* __restrict__ wgt,
                             unsigned short* __restrict__ wsA) {
    int e = blockIdx.x * 256 + threadIdx.x;
    if (e >= 9 * 2 * 64 * 8) return;
    int j    = e & 7;
    int lane = (e >> 3) & 63;
    int mt   = (e >> 9) & 1;
    int c    = e >> 10;
    int oc = mt * 16 + (lane & 15);
    int kk = ((lane >> 4) << 3) + j;
    wsA[e] = f2bf(wgt[oc * 432 + (kk >> 1) * 27 + (kk & 1) * 9 + c]);
}

// ---- fused main kernel ----
__global__ __launch_bounds__(512, 2) void depconv_fused(
    const float* __restrict__ feat,           // (4,16,512,512) fp32
    const int*   __restrict__ depth,          // (4,512,512)
    const unsigned short* __restrict__ wsA,
    float*       __restrict__ out)            // (4,32,512,512)
{
    __shared__ unsigned short ftile[TR + 2][TW + 2][PXS];   // 61,920 B
    __shared__ int            dtile[TR + 2][TW + 2];        //  6,192 B

    const int tid = threadIdx.x;

    // XCD bijective swizzle: 1024 blocks, 8 XCDs, 1024%8==0.
    const int bid = blockIdx.x;
    const int wg  = (bid & 7) * (1024 / 8) + (bid >> 3);

    const int b      = wg >> 8;            // image (256 blocks per image)
    const int rowblk = (wg >> 1) & 127;
    const int colblk = wg & 1;
    const int h0     = rowblk * TR;
    const int wstart = colblk * TW;

    // ---- stage 6x258 halo tile ----
    {
        const int h8 = tid >> 8;           // ic-half: ics 8*h8 .. 8*h8+7 (wave-uniform)
        const int xl = tid & 255;          // tile x (main body)
        const int x  = wstart - 1 + xl;
        const int xc = x < 0 ? 0 : (x > Ww - 1 ? Ww - 1 : x);
        const int xt  = wstart - 1 + 256 + xl;          // tail px 256,257 (xl<2)
        const int xct = xt > Ww - 1 ? Ww - 1 : xt;
        const float* fb  = feat + (size_t)(b * IC + 8 * h8) * HW;
        const int*   dbp = depth + (b << 18);
#pragma unroll
        for (int r = 0; r < 6; ++r) {
            int y = h0 - 1 + r;
            y = y < 0 ? 0 : (y > Hh - 1 ? Hh - 1 : y);
            const float* fpl = fb + (size_t)y * Ww;
            if (h8 == 0) {
                dtile[r][xl] = dbp[y * Ww + xc];
                if (xl < 2) dtile[r][256 + xl] = dbp[y * Ww + xct];
            }
            unsigned pk[4];
#pragma unroll
            for (int i = 0; i < 4; ++i) {
                float a = fpl[(size_t)(2 * i) * HW + xc];
                float c = fpl[(size_t)(2 * i + 1) * HW + xc];
                pk[i] = (unsigned)f2bf(a) | ((unsigned)f2bf(c) << 16);
            }
            unsigned short* wp = &ftile[r][xl][h8 * 8];
            *(uint2v*)wp       = (uint2v){pk[0], pk[1]};
            *(uint2v*)(wp + 4) = (uint2v){pk[2], pk[3]};
            if (xl < 2) {
                unsigned qk[4];
#pragma unroll
                for (int i = 0; i < 4; ++i) {
                    float a = fpl[(size_t)(2 * i) * HW + xct];
                    float c = fpl[(size_t)(2 * i + 1) * HW + xct];
                    qk[i] = (unsigned)f2bf(a) | ((unsigned)f2bf(c) << 16);
                }
                unsigned short* wq = &ftile[r][256 + xl][h8 * 8];
                *(uint2v*)wq       = (uint2v){qk[0], qk[1]};
                *(uint2v*)(wq + 4) = (uint2v){qk[2], qk[3]};
            }
        }
    }

    // A-fragments (global, all waves same -> L2 broadcast; no LDS dependency)
    const int lane = tid & 63;
    short8 afrag[9][2];
    {
        const short8* ap = (const short8*)wsA;
#pragma unroll
        for (int c = 0; c < 9; ++c) {
            afrag[c][0] = ap[(c * 2 + 0) * 64 + lane];
            afrag[c][1] = ap[(c * 2 + 1) * 64 + lane];
        }
    }
    __syncthreads();

    const int wv   = tid >> 6;
    const int g    = lane >> 4;     // ic-group: ics 4g..4g+3
    const int n    = lane & 15;
    const int rr   = wv >> 1;       // output row within tile: 0..3
    const int h    = h0 + rr;
    const int xoff = (wv & 1) * 128;

    const bool topE = (h == 0);
    const bool botE = (h == Hh - 1);

    float* opb = out + ((size_t)(b * OC) << 18) + (size_t)h * Ww;

    for (int it = 0; it < 8; ++it) {
        const int xb = xoff + it * 16 + n;      // tile px [0,256)
        const int w  = wstart + xb;             // global column
        const int dc = dtile[rr + 1][xb + 1];
        const bool lftE = (w == 0);
        const bool rgtE = (w == Ww - 1);

        float4v acc0 = {0.f, 0.f, 0.f, 0.f};
        float4v acc1 = {0.f, 0.f, 0.f, 0.f};

#pragma unroll
        for (int t = 0; t < 9; ++t) {
            const int kh = t / 3, kw = t % 3;
            unsigned mm;
            if (t == 4) {
                mm = 0xffff0000u;   // center: diff==0 always, kd=1 slice
            } else {
                const bool inb = !((kh == 0 && topE) || (kh == 2 && botE) ||
                                   (kw == 0 && lftE) || (kw == 2 && rgtE));
                const int diff = dtile[rr + kh][xb + kw] - dc;
                mm = (diff == 0) ? 0xffff0000u : ((diff == -1) ? 0x0000ffffu : 0u);
                if (!inb) mm = 0u;
            }
            // 4 ics of this lane's neighbor pixel: one 8 B LDS read,
            // single base VGPR + immediate offset ((kh*258+kw)*40 < 64 KiB).
            const uint2v pr = *(const uint2v*)(&ftile[rr + kh][xb + kw][g << 2]);
            union { short8 s; unsigned u[4]; } bf;
            bf.u[0] = __builtin_amdgcn_perm(0u, pr.x, 0x01000100u) & mm;  // ic 4g+0
            bf.u[1] = __builtin_amdgcn_perm(0u, pr.x, 0x03020302u) & mm;  // ic 4g+1
            bf.u[2] = __builtin_amdgcn_perm(0u, pr.y, 0x01000100u) & mm;  // ic 4g+2
            bf.u[3] = __builtin_amdgcn_perm(0u, pr.y, 0x03020302u) & mm;  // ic 4g+3

            acc0 = __builtin_amdgcn_mfma_f32_16x16x32_bf16(afrag[t][0], bf.s, acc0, 0, 0, 0);
            acc1 = __builtin_amdgcn_mfma_f32_16x16x32_bf16(afrag[t][1], bf.s, acc1, 0, 0, 0);
        }

        const int rbase = g * 4;
        float* op = opb + w;
#pragma unroll
        for (int r = 0; r < 4; ++r) {
            op[(size_t)(rbase + r) * HW]      = acc0[r];
            op[(size_t)(16 + rbase + r) * HW] = acc1[r];
        }
    }
}

extern "C" void kernel_launch(void* const* d_in, const int* in_sizes, int n_in,
                              void* d_out, int out_size, void* d_ws, size_t ws_size,
                              hipStream_t stream) {
    const float* feat  = (const float*)d_in[0];
    const int*   depth = (const int*)d_in[1];
    const float* wgt   = (const float*)d_in[2];
    float* out = (float*)d_out;

    unsigned short* wsA = (unsigned short*)d_ws;     // 18,432 B only

    prep_weights<<<36, 256, 0, stream>>>(wgt, wsA);
    depconv_fused<<<1024, 512, 0, stream>>>(feat, depth, wsA, out);
}

// Round 4
// 213.998 us; speedup vs baseline: 1.5620x; 1.0454x over previous
//
#include <hip/hip_runtime.h>
#include <hip/hip_bf16.h>

// DepConv3D, fused single-pass, 4-row x 256-px tile, 512 threads (8 waves).
//   diff = depth[nbr]-depth[center]; kd=0 iff diff==-1, kd=1 iff diff==0, else 0.
// Block stages a 6x258 halo tile (bf16 pixel-major features, 40 B padded px
// stride + int depth) in LDS once, then each wave runs the 9-tap MFMA loop for
// one half-row (8 its x 16 px) reading LDS only (base VGPR + imm offsets).
// R4 changes vs R3 (90 us, MfmaUtil 8%, VALUBusy 22% -> latency-bound):
//   - SENTINEL depth (1<<20) staged for out-of-image halo cells: inner loop
//     drops all boundary predicates (mask is 0 automatically via diff).
//   - bf16 packing via __float22bfloat162_rn pairs -> v_cvt_pk_bf16_f32
//     (1 op vs ~7 manual RNE ops per pair) in the staging phase.
//   - s_setprio(1) around each MFMA pair (T5: stage/compute wave diversity).
// __launch_bounds__(512, 2): (512,4) capped alloc at 64 VGPRs -> scratch
// spill catastrophe (R2: WRITE_SIZE 320 MB). 76 VGPRs -> 16 waves/CU.
// MFMA 16x16x32_bf16 conventions (validated by previous passing runs):
//   A: m=lane&15 (oc), kk=(lane>>4)*8+j ; B: n=lane&15 (pixel), kk same
//   D: col=lane&15 (pixel), row=(lane>>4)*4+r (oc)

#define IC 16
#define OC 32
#define Hh 512
#define Ww 512
#define HW (Hh * Ww)
#define TW 256          // tile width  (output px)
#define TR 4            // tile rows   (output)
#define PXS 20          // shorts per px in LDS (40 B, padded from 32)
#define SENT (1 << 20)  // sentinel depth: diff never in {0,-1}

typedef __attribute__((ext_vector_type(8))) short short8;
typedef __attribute__((ext_vector_type(4))) float float4v;
typedef __attribute__((ext_vector_type(2))) unsigned int uint2v;

__device__ __forceinline__ unsigned short f2bf(float x) {
    unsigned u = __float_as_uint(x);
    unsigned r = u + 0x7FFFu + ((u >> 16) & 1u);   // RNE
    return (unsigned short)(r >> 16);
}

// packed RNE pair via v_cvt_pk_bf16_f32 (compiler fuses _rn cast pairs)
__device__ __forceinline__ unsigned packbf(float a, float b) {
    union { __hip_bfloat162 h2; unsigned u; } cv;
    cv.h2 = __float22bfloat162_rn(make_float2(a, b));
    return cv.u;
}

// ---- prepass: fp32 weights (32,16,3,3,3) -> bf16 A-fragments ----
__global__ void prep_weights(const float* __restrict__ wgt,
                             unsigned short* __restrict__ wsA) {
    int e = blockIdx.x * 256 + threadIdx.x;
    if (e >= 9 * 2 * 64 * 8) return;
    int j    = e & 7;
    int lane = (e >> 3) & 63;
    int mt   = (e >> 9) & 1;
    int c    = e >> 10;
    int oc = mt * 16 + (lane & 15);
    int kk = ((lane >> 4) << 3) + j;
    wsA[e] = f2bf(wgt[oc * 432 + (kk >> 1) * 27 + (kk & 1) * 9 + c]);
}

// ---- fused main kernel ----
__global__ __launch_bounds__(512, 2) void depconv_fused(
    const float* __restrict__ feat,           // (4,16,512,512) fp32
    const int*   __restrict__ depth,          // (4,512,512)
    const unsigned short* __restrict__ wsA,
    float*       __restrict__ out)            // (4,32,512,512)
{
    __shared__ unsigned short ftile[TR + 2][TW + 2][PXS];   // 61,920 B
    __shared__ int            dtile[TR + 2][TW + 2];        //  6,192 B

    const int tid = threadIdx.x;

    // XCD bijective swizzle: 1024 blocks, 8 XCDs, 1024%8==0.
    const int bid = blockIdx.x;
    const int wg  = (bid & 7) * (1024 / 8) + (bid >> 3);

    const int b      = wg >> 8;            // image (256 blocks per image)
    const int rowblk = (wg >> 1) & 127;
    const int colblk = wg & 1;
    const int h0     = rowblk * TR;
    const int wstart = colblk * TW;

    // ---- stage 6x258 halo tile ----
    {
        const int h8 = tid >> 8;           // ic-half: ics 8*h8 .. 8*h8+7 (wave-uniform)
        const int xl = tid & 255;          // tile x (main body)
        const int x  = wstart - 1 + xl;
        const bool xin = (unsigned)x < (unsigned)Ww;
        const int xc = x < 0 ? 0 : (x > Ww - 1 ? Ww - 1 : x);
        const int xt  = wstart - 1 + 256 + xl;          // tail px 256,257 (xl<2)
        const bool xtin = (unsigned)xt < (unsigned)Ww;
        const int xct = xt > Ww - 1 ? Ww - 1 : xt;
        const float* fb  = feat + (size_t)(b * IC + 8 * h8) * HW;
        const int*   dbp = depth + (b << 18);
#pragma unroll
        for (int r = 0; r < 6; ++r) {
            const int y = h0 - 1 + r;
            const bool yin = (unsigned)y < (unsigned)Hh;
            const int yc = y < 0 ? 0 : (y > Hh - 1 ? Hh - 1 : y);
            const float* fpl = fb + (size_t)yc * Ww;
            if (h8 == 0) {
                dtile[r][xl] = (yin & xin) ? dbp[yc * Ww + xc] : SENT;
                if (xl < 2)
                    dtile[r][256 + xl] = (yin & xtin) ? dbp[yc * Ww + xct] : SENT;
            }
            unsigned pk[4];
#pragma unroll
            for (int i = 0; i < 4; ++i)
                pk[i] = packbf(fpl[(size_t)(2 * i) * HW + xc],
                               fpl[(size_t)(2 * i + 1) * HW + xc]);
            unsigned short* wp = &ftile[r][xl][h8 * 8];
            *(uint2v*)wp       = (uint2v){pk[0], pk[1]};
            *(uint2v*)(wp + 4) = (uint2v){pk[2], pk[3]};
            if (xl < 2) {
                unsigned qk[4];
#pragma unroll
                for (int i = 0; i < 4; ++i)
                    qk[i] = packbf(fpl[(size_t)(2 * i) * HW + xct],
                                   fpl[(size_t)(2 * i + 1) * HW + xct]);
                unsigned short* wq = &ftile[r][256 + xl][h8 * 8];
                *(uint2v*)wq       = (uint2v){qk[0], qk[1]};
                *(uint2v*)(wq + 4) = (uint2v){qk[2], qk[3]};
            }
        }
    }

    // A-fragments (global, all waves same -> L2 broadcast; no LDS dependency)
    const int lane = tid & 63;
    short8 afrag[9][2];
    {
        const short8* ap = (const short8*)wsA;
#pragma unroll
        for (int c = 0; c < 9; ++c) {
            afrag[c][0] = ap[(c * 2 + 0) * 64 + lane];
            afrag[c][1] = ap[(c * 2 + 1) * 64 + lane];
        }
    }
    __syncthreads();

    const int wv   = tid >> 6;
    const int g    = lane >> 4;     // ic-group: ics 4g..4g+3
    const int n    = lane & 15;
    const int rr   = wv >> 1;       // output row within tile: 0..3
    const int h    = h0 + rr;
    const int xoff = (wv & 1) * 128;

    float* opb = out + ((size_t)(b * OC) << 18) + (size_t)h * Ww;

    for (int it = 0; it < 8; ++it) {
        const int xb = xoff + it * 16 + n;      // tile px [0,256)
        const int w  = wstart + xb;             // global column
        const int dc = dtile[rr + 1][xb + 1];

        float4v acc0 = {0.f, 0.f, 0.f, 0.f};
        float4v acc1 = {0.f, 0.f, 0.f, 0.f};

#pragma unroll
        for (int t = 0; t < 9; ++t) {
            const int kh = t / 3, kw = t % 3;
            unsigned mm;
            if (t == 4) {
                mm = 0xffff0000u;   // center: diff==0 always, kd=1 slice
            } else {
                // sentinel-staged depth: out-of-image diff is huge -> mm = 0
                const int diff = dtile[rr + kh][xb + kw] - dc;
                mm = (diff == 0) ? 0xffff0000u : ((diff == -1) ? 0x0000ffffu : 0u);
            }
            // 4 ics of this lane's neighbor pixel: one 8 B LDS read,
            // single base VGPR + immediate offset ((kh*258+kw)*40 < 64 KiB).
            const uint2v pr = *(const uint2v*)(&ftile[rr + kh][xb + kw][g << 2]);
            union { short8 s; unsigned u[4]; } bf;
            bf.u[0] = __builtin_amdgcn_perm(0u, pr.x, 0x01000100u) & mm;  // ic 4g+0
            bf.u[1] = __builtin_amdgcn_perm(0u, pr.x, 0x03020302u) & mm;  // ic 4g+1
            bf.u[2] = __builtin_amdgcn_perm(0u, pr.y, 0x01000100u) & mm;  // ic 4g+2
            bf.u[3] = __builtin_amdgcn_perm(0u, pr.y, 0x03020302u) & mm;  // ic 4g+3

            __builtin_amdgcn_s_setprio(1);
            acc0 = __builtin_amdgcn_mfma_f32_16x16x32_bf16(afrag[t][0], bf.s, acc0, 0, 0, 0);
            acc1 = __builtin_amdgcn_mfma_f32_16x16x32_bf16(afrag[t][1], bf.s, acc1, 0, 0, 0);
            __builtin_amdgcn_s_setprio(0);
        }

        const int rbase = g * 4;
        float* op = opb + w;
#pragma unroll
        for (int r = 0; r < 4; ++r) {
            op[(size_t)(rbase + r) * HW]      = acc0[r];
            op[(size_t)(16 + rbase + r) * HW] = acc1[r];
        }
    }
}

extern "C" void kernel_launch(void* const* d_in, const int* in_sizes, int n_in,
                              void* d_out, int out_size, void* d_ws, size_t ws_size,
                              hipStream_t stream) {
    const float* feat  = (const float*)d_in[0];
    const int*   depth = (const int*)d_in[1];
    const float* wgt   = (const float*)d_in[2];
    float* out = (float*)d_out;

    unsigned short* wsA = (unsigned short*)d_ws;     // 18,432 B only

    prep_weights<<<36, 256, 0, stream>>>(wgt, wsA);
    depconv_fused<<<1024, 512, 0, stream>>>(feat, depth, wsA, out);
}

// Round 5
// 213.820 us; speedup vs baseline: 1.5633x; 1.0008x over previous
//
#include <hip/hip_runtime.h>
#include <hip/hip_bf16.h>

// DepConv3D, fused single-pass, 4-row x 256-px tile, 512 threads (8 waves).
//   diff = depth[nbr]-depth[center]; kd=0 iff diff==-1, kd=1 iff diff==0, else 0.
// Block stages a 6x258 halo tile in LDS once (bf16 pixel-major features, depth
// as u16 with sentinel), then each wave runs the 9-tap MFMA loop for one
// half-row (8 its x 16 px) reading LDS only.
// R5 changes vs R4 (91 us, unchanged vs R3; VGPR 56 + 17 MB scratch writes):
//   - removed per-tap s_setprio pairs (72 sched-region splits/thread; prime
//     suspect for the VGPR-56 spill codegen).
//   - LDS diet for 3 blocks/CU (24 waves/CU, was 16): dense 32 B px stride
//     with chunk XOR-swizzle slot = g ^ ((px>>2)&3) -> conflict-free for both
//     ds_write_b64 staging and ds_read_b64 compute (2 words/bank per 32-lane
//     phase); depth tile as u16, sentinel 0x1000. LDS 68,112 -> 52,632 B.
//   - kept R4 wins: sentinel depth kills inner-loop boundary predicates;
//     v_cvt_pk_bf16_f32 packing via __float22bfloat162_rn.
// __launch_bounds__(512, 2): (512,4) hard-capped alloc at 64 VGPRs -> scratch
// spill catastrophe (R2: WRITE_SIZE 320 MB). Cap 128; want compiled <=85 so
// HW occupancy reaches the LDS-allowed 6 waves/SIMD.
// MFMA 16x16x32_bf16 conventions (validated by previous passing runs):
//   A: m=lane&15 (oc), kk=(lane>>4)*8+j ; B: n=lane&15 (pixel), kk same
//   D: col=lane&15 (pixel), row=(lane>>4)*4+r (oc)

#define IC 16
#define OC 32
#define Hh 512
#define Ww 512
#define HW (Hh * Ww)
#define TW 256            // tile width  (output px)
#define TR 4              // tile rows   (output)
#define ROWSH 4128        // shorts per ftile row: 258 px * 16 sh
#define SENT 0x1000       // sentinel depth (u16): diff never in {0,-1}

typedef __attribute__((ext_vector_type(8))) short short8;
typedef __attribute__((ext_vector_type(4))) float float4v;
typedef __attribute__((ext_vector_type(2))) unsigned int uint2v;

__device__ __forceinline__ unsigned short f2bf(float x) {
    unsigned u = __float_as_uint(x);
    unsigned r = u + 0x7FFFu + ((u >> 16) & 1u);   // RNE
    return (unsigned short)(r >> 16);
}

// packed RNE pair via v_cvt_pk_bf16_f32 (compiler fuses _rn cast pairs)
__device__ __forceinline__ unsigned packbf(float a, float b) {
    union { __hip_bfloat162 h2; unsigned u; } cv;
    cv.h2 = __float22bfloat162_rn(make_float2(a, b));
    return cv.u;
}

// ---- prepass: fp32 weights (32,16,3,3,3) -> bf16 A-fragments ----
__global__ void prep_weights(const float* __restrict__ wgt,
                             unsigned short* __restrict__ wsA) {
    int e = blockIdx.x * 256 + threadIdx.x;
    if (e >= 9 * 2 * 64 * 8) return;
    int j    = e & 7;
    int lane = (e >> 3) & 63;
    int mt   = (e >> 9) & 1;
    int c    = e >> 10;
    int oc = mt * 16 + (lane & 15);
    int kk = ((lane >> 4) << 3) + j;
    wsA[e] = f2bf(wgt[oc * 432 + (kk >> 1) * 27 + (kk & 1) * 9 + c]);
}

// ---- fused main kernel ----
__global__ __launch_bounds__(512, 2) void depconv_fused(
    const float* __restrict__ feat,           // (4,16,512,512) fp32
    const int*   __restrict__ depth,          // (4,512,512)
    const unsigned short* __restrict__ wsA,
    float*       __restrict__ out)            // (4,32,512,512)
{
    __shared__ unsigned short ftile[6 * ROWSH];             // 49,536 B
    __shared__ unsigned short dtile[6][TW + 2];             //  3,096 B

    const int tid = threadIdx.x;

    // XCD bijective swizzle: 1024 blocks, 8 XCDs, 1024%8==0.
    const int bid = blockIdx.x;
    const int wg  = (bid & 7) * (1024 / 8) + (bid >> 3);

    const int b      = wg >> 8;            // image (256 blocks per image)
    const int rowblk = (wg >> 1) & 127;
    const int colblk = wg & 1;
    const int h0     = rowblk * TR;
    const int wstart = colblk * TW;

    // ---- stage 6x258 halo tile ----
    {
        const int h8 = tid >> 8;           // ic-half: ics 8*h8..8*h8+7 (wave-uniform)
        const int xl = tid & 255;          // tile x (main body)
        const int x  = wstart - 1 + xl;
        const bool xin = (unsigned)x < (unsigned)Ww;
        const int xc = x < 0 ? 0 : (x > Ww - 1 ? Ww - 1 : x);
        const int xt  = wstart - 1 + 256 + xl;          // tail px 256,257 (xl<2)
        const bool xtin = (unsigned)xt < (unsigned)Ww;
        const int xct = xt > Ww - 1 ? Ww - 1 : xt;
        const int qx = (xl >> 2) & 3;      // swizzle nibble for main-body px
        // tail px 256,257: ((256+xl)>>2)&3 == 0 for xl<2
        const float* fb  = feat + (size_t)(b * IC + 8 * h8) * HW;
        const int*   dbp = depth + (b << 18);
#pragma unroll
        for (int r = 0; r < 6; ++r) {
            const int y = h0 - 1 + r;
            const bool yin = (unsigned)y < (unsigned)Hh;
            const int yc = y < 0 ? 0 : (y > Hh - 1 ? Hh - 1 : y);
            const float* fpl = fb + (size_t)yc * Ww;
            if (h8 == 0) {
                dtile[r][xl] = (yin & xin) ? (unsigned short)dbp[yc * Ww + xc] : (unsigned short)SENT;
                if (xl < 2)
                    dtile[r][256 + xl] = (yin & xtin) ? (unsigned short)dbp[yc * Ww + xct]
                                                      : (unsigned short)SENT;
            }
            unsigned pk[4];
#pragma unroll
            for (int i = 0; i < 4; ++i)
                pk[i] = packbf(fpl[(size_t)(2 * i) * HW + xc],
                               fpl[(size_t)(2 * i + 1) * HW + xc]);
            // two swizzled 8 B chunk writes: logical chunks 2*h8, 2*h8+1
            unsigned short* wp = &ftile[r * ROWSH + xl * 16];
            *(uint2v*)(wp + ((((2 * h8)     ) ^ qx) << 2)) = (uint2v){pk[0], pk[1]};
            *(uint2v*)(wp + ((((2 * h8) + 1) ^ qx) << 2)) = (uint2v){pk[2], pk[3]};
            if (xl < 2) {
                unsigned qk[4];
#pragma unroll
                for (int i = 0; i < 4; ++i)
                    qk[i] = packbf(fpl[(size_t)(2 * i) * HW + xct],
                                   fpl[(size_t)(2 * i + 1) * HW + xct]);
                unsigned short* wq = &ftile[r * ROWSH + (256 + xl) * 16];
                *(uint2v*)(wq + (((2 * h8)     ) << 2)) = (uint2v){qk[0], qk[1]};  // q=0
                *(uint2v*)(wq + (((2 * h8) + 1) << 2)) = (uint2v){qk[2], qk[3]};
            }
        }
    }

    // A-fragments (global, all waves same -> L2 broadcast; no LDS dependency)
    const int lane = tid & 63;
    short8 afrag[9][2];
    {
        const short8* ap = (const short8*)wsA;
#pragma unroll
        for (int c = 0; c < 9; ++c) {
            afrag[c][0] = ap[(c * 2 + 0) * 64 + lane];
            afrag[c][1] = ap[(c * 2 + 1) * 64 + lane];
        }
    }
    __syncthreads();

    const int wv   = tid >> 6;
    const int g    = lane >> 4;     // ic-group: ics 4g..4g+3
    const int n    = lane & 15;
    const int rr   = wv >> 1;       // output row within tile: 0..3
    const int h    = h0 + rr;
    const int xoff = (wv & 1) * 128;

    float* opb = out + ((size_t)(b * OC) << 18) + (size_t)h * Ww;
    const unsigned short* frow0 = &ftile[rr * ROWSH];

    for (int it = 0; it < 8; ++it) {
        const int xb = xoff + it * 16 + n;      // tile px [0,256)
        const int w  = wstart + xb;             // global column
        const int dc = dtile[rr + 1][xb + 1];

        // per-it swizzled column addresses for kw=0,1,2 (kh folds into the
        // ds offset immediate: (rr+kh)*ROWSH*2 with kh in {0,1,2})
        const unsigned short* colp[3];
#pragma unroll
        for (int kw = 0; kw < 3; ++kw) {
            const int px = xb + kw;
            const int q  = (px >> 2) & 3;
            colp[kw] = frow0 + px * 16 + ((g ^ q) << 2);
        }

        float4v acc0 = {0.f, 0.f, 0.f, 0.f};
        float4v acc1 = {0.f, 0.f, 0.f, 0.f};

#pragma unroll
        for (int t = 0; t < 9; ++t) {
            const int kh = t / 3, kw = t % 3;
            unsigned mm;
            if (t == 4) {
                mm = 0xffff0000u;   // center: diff==0 always, kd=1 slice
            } else {
                // sentinel-staged depth: out-of-image diff is huge -> mm = 0
                const int diff = (int)dtile[rr + kh][xb + kw] - dc;
                mm = (diff == 0) ? 0xffff0000u : ((diff == -1) ? 0x0000ffffu : 0u);
            }
            // 4 ics of this lane's neighbor pixel: one 8 B LDS read at the
            // swizzled chunk slot; row term kh*8256 B is an immediate.
            const uint2v pr = *(const uint2v*)(colp[kw] + kh * ROWSH);
            union { short8 s; unsigned u[4]; } bf;
            bf.u[0] = __builtin_amdgcn_perm(0u, pr.x, 0x01000100u) & mm;  // ic 4g+0
            bf.u[1] = __builtin_amdgcn_perm(0u, pr.x, 0x03020302u) & mm;  // ic 4g+1
            bf.u[2] = __builtin_amdgcn_perm(0u, pr.y, 0x01000100u) & mm;  // ic 4g+2
            bf.u[3] = __builtin_amdgcn_perm(0u, pr.y, 0x03020302u) & mm;  // ic 4g+3

            acc0 = __builtin_amdgcn_mfma_f32_16x16x32_bf16(afrag[t][0], bf.s, acc0, 0, 0, 0);
            acc1 = __builtin_amdgcn_mfma_f32_16x16x32_bf16(afrag[t][1], bf.s, acc1, 0, 0, 0);
        }

        const int rbase = g * 4;
        float* op = opb + w;
#pragma unroll
        for (int r = 0; r < 4; ++r) {
            op[(size_t)(rbase + r) * HW]      = acc0[r];
            op[(size_t)(16 + rbase + r) * HW] = acc1[r];
        }
    }
}

extern "C" void kernel_launch(void* const* d_in, const int* in_sizes, int n_in,
                              void* d_out, int out_size, void* d_ws, size_t ws_size,
                              hipStream_t stream) {
    const float* feat  = (const float*)d_in[0];
    const int*   depth = (const int*)d_in[1];
    const float* wgt   = (const float*)d_in[2];
    float* out = (float*)d_out;

    unsigned short* wsA = (unsigned short*)d_ws;     // 18,432 B only

    prep_weights<<<36, 256, 0, stream>>>(wgt, wsA);
    depconv_fused<<<1024, 512, 0, stream>>>(feat, depth, wsA, out);
}